// Round 11
// baseline (343.516 us; speedup 1.0000x reference)
//
#include <hip/hip_runtime.h>
#include <hip/hip_bf16.h>

#define TT 512
#define DD 512
#define VV 2048
#define HH 128

typedef __attribute__((ext_vector_type(8))) short bf16x8;
typedef __attribute__((ext_vector_type(8))) unsigned short ushort8;
typedef __attribute__((ext_vector_type(4))) unsigned short ushort4v;
typedef __attribute__((ext_vector_type(4))) float f32x4;

__device__ __forceinline__ unsigned short f2bf(float f) {
  union { __hip_bfloat16 b; unsigned short u; } cv;
  cv.b = __float2bfloat16(f);
  return cv.u;
}

// LDS-only barrier: orders ds ops across waves without draining vmcnt.
__device__ __forceinline__ void lds_barrier() {
  asm volatile("s_waitcnt lgkmcnt(0)\n\ts_barrier" ::: "memory");
}

// Counted vmem gate (per-wave): keep the youngest N vmem ops in flight.
#define VM_GATE(N)                                                   \
  do {                                                               \
    asm volatile("s_waitcnt vmcnt(" #N ")" ::: "memory");            \
    __builtin_amdgcn_sched_barrier(0);                               \
  } while (0)

__global__ void cvt_x_kernel(const float* __restrict__ x, unsigned short* __restrict__ xb) {
  const int i = blockIdx.x * blockDim.x + threadIdx.x;
  const float4 f = ((const float4*)x)[i];
  ushort4v u;
  u[0] = f2bf(f.x); u[1] = f2bf(f.y); u[2] = f2bf(f.z); u[3] = f2bf(f.w);
  ((ushort4v*)xb)[i] = u;
}

// 2 WGs per voxel (half = 256 t-rows each), XCD-paired so W1[v] is HBM-fetched
// once and L2-served to the twin. 512 thr = 8 waves; wave w owns 32 t-rows.
// Phase A (K=512, 16 steps of BK=32): W1 fp32 tile [32k][128h] DMA'd via
// global_load_lds into a ring-3; EACH WAVE CONVERTS THE 4 ROWS IT DMA'D
// (per-wave vmcnt gate alone orders DMA->convert; no barrier in between).
// One lds_barrier per step publishes the bf16 frag tile F (dbuf).
// LDS (64 KiB): G ring 3x16K [0,49152) + F 2x8K [49152,65536) (phase A);
//               W2L [0,32768) + h1 slots 8x4K [32768,65536) (phase B).
__global__ __launch_bounds__(512, 4)
void voxel_mlp_kernel(const unsigned short* __restrict__ Xb,
                      const float* __restrict__ W1,
                      const float* __restrict__ b1,
                      const float* __restrict__ W2,
                      const float* __restrict__ b2,
                      const float* __restrict__ W3,
                      const float* __restrict__ b3,
                      float* __restrict__ out) {
  __shared__ __align__(16) char LDS[65536];
  constexpr unsigned GBASE  = 0;
  constexpr unsigned FBASE  = 49152;
  constexpr unsigned W2BASE = 0;
  constexpr unsigned H1BASE = 32768;

  const int bid  = blockIdx.x;
  const int xcd  = bid & 7;
  const int gg   = bid >> 3;
  const int half = gg & 1;
  const int v    = (gg >> 1) * 8 + xcd;   // twin halves share an XCD

  const int tid = threadIdx.x;
  const int w   = tid >> 6;
  const int l   = tid & 63;
  const int lg  = l >> 4;
  const int ll  = l & 15;

  const float* W1v = W1 + (size_t)v * DD * HH;
  const float* W2v = W2 + (size_t)v * HH * HH;

  // DMA source: lane covers row w*4 + p*2 + (l>>5), dwords (l&31)*4..+3
  const size_t gsrc = (size_t)((w * 4 + (l >> 5)) * HH + (l & 31) * 4);
  // convert lane mapping: n-block n_c, col pair (ll0, ll0+1)
  const int n_c = l >> 3;
  const int ll0 = (l & 7) * 2;

#define G_ISSUE(t)                                                          \
  { const float* gp = W1v + (size_t)(t) * 32 * HH + gsrc;                   \
    const unsigned ldst = GBASE + (unsigned)((t) % 3) * 16384u +            \
                          (unsigned)w * 2048u;                              \
    _Pragma("unroll") for (int p = 0; p < 2; ++p)                           \
      __builtin_amdgcn_global_load_lds(                                     \
        (const __attribute__((address_space(1))) void*)(gp + p * 2 * HH),   \
        (__attribute__((address_space(3))) void*)(&LDS[ldst + p * 1024u]),  \
        16, 0, 0); }

// convert OWN rows (w*4..+3) of tile tau from G-ring to frag tile F
#define CVT(tau)                                                            \
  { const unsigned gs = GBASE + (unsigned)((tau) % 3) * 16384u;             \
    ushort4v ev, ov;                                                        \
    _Pragma("unroll") for (int r = 0; r < 4; ++r) {                         \
      const float2 g2 = *(const float2*)(&LDS[gs +                          \
          (unsigned)((w * 4 + r) * 512 + (n_c * 16 + ll0) * 4)]);           \
      ev[r] = f2bf(g2.x); ov[r] = f2bf(g2.y); }                             \
    const unsigned fb = FBASE + (unsigned)((tau) & 1) * 8192u +             \
                        (unsigned)n_c * 1024u;                              \
    const unsigned ca = (unsigned)((((w >> 1) * 16 + ll0) * 16) ^ (n_c << 4)); \
    const unsigned cb = (unsigned)((((w >> 1) * 16 + ll0 + 1) * 16) ^ (n_c << 4)); \
    *(ushort4v*)(&LDS[fb + ca + (unsigned)(w & 1) * 8u]) = ev;              \
    *(ushort4v*)(&LDS[fb + cb + (unsigned)(w & 1) * 8u]) = ov; }

  // ---- prologue ----
  G_ISSUE(0);
  G_ISSUE(1);
  VM_GATE(2);      // own tile-0 ops landed; tile-1 in flight
  CVT(0);
  lds_barrier();

  f32x4 acc1[2][8];
#pragma unroll
  for (int mi = 0; mi < 2; ++mi)
#pragma unroll
    for (int n = 0; n < 8; ++n) acc1[mi][n] = f32x4{0.f, 0.f, 0.f, 0.f};

  // ---- phase A: 16 steps of BK=32, ONE barrier per step ----
#pragma unroll
  for (int s = 0; s < 16; ++s) {
    // A-frags first (oldest): retired by the gate, never drain the DMA ring
    bf16x8 aF[2];
#pragma unroll
    for (int mi = 0; mi < 2; ++mi)
      aF[mi] = *(const bf16x8*)(Xb + (size_t)(half * 256 + w * 32 + mi * 16 + ll) * DD +
                                s * 32 + lg * 8);
    __builtin_amdgcn_sched_barrier(0);

    if (s < 14) {
      G_ISSUE(s + 2);
      VM_GATE(2);        // retires A + tile s+1; keeps tile s+2 in flight
    } else if (s == 14) {
      VM_GATE(0);        // last tile (15) must land; nothing younger to keep
    }

    if (s < 15) CVT(s + 1);   // own rows; writes F[(s+1)&1]

    // 16 MFMAs on F[s&1] (published by previous step's barrier)
#pragma unroll
    for (int n = 0; n < 8; ++n) {
      const bf16x8 b = *(const bf16x8*)(&LDS[FBASE + (unsigned)(s & 1) * 8192u +
                                             (unsigned)n * 1024u +
                                             (unsigned)(((lg * 16 + ll) * 16) ^ (n << 4))]);
#pragma unroll
      for (int mi = 0; mi < 2; ++mi)
        acc1[mi][n] = __builtin_amdgcn_mfma_f32_16x16x32_bf16(aF[mi], b, acc1[mi][n], 0, 0, 0);
    }
    lds_barrier();
  }
#undef G_ISSUE
#undef CVT

  // ---- phase B setup (G/F regions dead after final barrier) ----
  float b1v[8], b2v[8], w3v[8];
#pragma unroll
  for (int n = 0; n < 8; ++n) {
    b1v[n] = b1[v * HH + n * 16 + ll];
    b2v[n] = b2[v * HH + n * 16 + ll];
    w3v[n] = W3[v * HH + n * 16 + ll];
  }
  const float b3v = b3[v];

  // W2 -> LDS frag-linear [ki][m]: wave w stages ki=w&3, m-block (w>>2)*4+q
  {
    const int ki = w & 3, mb = (w >> 2) * 4;
    float w2t[4][8];
#pragma unroll
    for (int q = 0; q < 4; ++q)
#pragma unroll
      for (int j = 0; j < 8; ++j)
        w2t[q][j] = W2v[(ki * 32 + lg * 8 + j) * HH + (mb + q) * 16 + ll];
#pragma unroll
    for (int q = 0; q < 4; ++q) {
      ushort8 e;
#pragma unroll
      for (int j = 0; j < 8; ++j) e[j] = f2bf(w2t[q][j]);
      *(ushort8*)(&LDS[W2BASE + (unsigned)ki * 8192u + (unsigned)(mb + q) * 1024u +
                       (unsigned)l * 16u]) = e;
    }
  }
  lds_barrier();   // W2L visible

  const unsigned slot = H1BASE + (unsigned)w * 4096u;  // wave-private 16x128 bf16

  // ---- phase B: layers 2+3, two 16-row chunks per wave ----
#pragma unroll
  for (int mi = 0; mi < 2; ++mi) {
#pragma unroll
    for (int n = 0; n < 8; ++n) {
#pragma unroll
      for (int r = 0; r < 4; ++r) {
        const int tl = lg * 4 + r;
        float hv = acc1[mi][n][r] + b1v[n];
        hv = fmaxf(hv, 0.f);
        const int h = n * 16 + ll;
        const unsigned byte = slot + (unsigned)tl * 256u +
                              (unsigned)((h * 2) ^ ((tl & 7) << 4));
        *(unsigned short*)(&LDS[byte]) = f2bf(hv);
      }
    }
    f32x4 acc2[8];
#pragma unroll
    for (int m = 0; m < 8; ++m) acc2[m] = f32x4{0.f, 0.f, 0.f, 0.f};
#pragma unroll
    for (int ki = 0; ki < 4; ++ki) {
      const int k0 = ki * 32 + lg * 8;
      const unsigned abyte = slot + (unsigned)ll * 256u +
                             (unsigned)((k0 * 2) ^ ((ll & 7) << 4));
      const bf16x8 a2 = *(const bf16x8*)(&LDS[abyte]);
#pragma unroll
      for (int m = 0; m < 8; ++m) {
        const bf16x8 bw = *(const bf16x8*)(&LDS[W2BASE + (unsigned)ki * 8192u +
                                                (unsigned)m * 1024u + (unsigned)l * 16u]);
        acc2[m] = __builtin_amdgcn_mfma_f32_16x16x32_bf16(a2, bw, acc2[m], 0, 0, 0);
      }
    }
#pragma unroll
    for (int r = 0; r < 4; ++r) {
      float p = 0.f;
#pragma unroll
      for (int m = 0; m < 8; ++m)
        p += fmaxf(acc2[m][r] + b2v[m], 0.f) * w3v[m];
      p += __shfl_xor(p, 1);
      p += __shfl_xor(p, 2);
      p += __shfl_xor(p, 4);
      p += __shfl_xor(p, 8);
      if (ll == 0) {
        const int t = half * 256 + w * 32 + mi * 16 + lg * 4 + r;
        out[t * VV + v] = p + b3v;
      }
    }
  }
}

extern "C" void kernel_launch(void* const* d_in, const int* in_sizes, int n_in,
                              void* d_out, int out_size, void* d_ws, size_t ws_size,
                              hipStream_t stream) {
  const float* X  = (const float*)d_in[0];
  const float* W1 = (const float*)d_in[1];
  const float* b1 = (const float*)d_in[2];
  const float* W2 = (const float*)d_in[3];
  const float* b2 = (const float*)d_in[4];
  const float* W3 = (const float*)d_in[5];
  const float* b3 = (const float*)d_in[6];
  float* out = (float*)d_out;

  unsigned short* Xb = (unsigned short*)d_ws;   // 512 KiB bf16 X

  cvt_x_kernel<<<256, 256, 0, stream>>>(X, Xb);
  voxel_mlp_kernel<<<VV * 2, 512, 0, stream>>>(Xb, W1, b1, W2, b2, W3, b3, out);
}

// Round 12
// 293.107 us; speedup vs baseline: 1.1720x; 1.1720x over previous
//
#include <hip/hip_runtime.h>
#include <hip/hip_bf16.h>

#define TT 512
#define DD 512
#define VV 2048
#define HH 128

typedef __attribute__((ext_vector_type(8))) short bf16x8;
typedef __attribute__((ext_vector_type(8))) unsigned short ushort8;
typedef __attribute__((ext_vector_type(4))) unsigned short ushort4v;
typedef __attribute__((ext_vector_type(4))) float f32x4;

__device__ __forceinline__ unsigned short f2bf(float f) {
  union { __hip_bfloat16 b; unsigned short u; } cv;
  cv.b = __float2bfloat16(f);
  return cv.u;
}

// LDS-only barrier: orders ds ops across waves without draining vmcnt.
__device__ __forceinline__ void lds_barrier() {
  asm volatile("s_waitcnt lgkmcnt(0)\n\ts_barrier" ::: "memory");
}

// Counted vmem gate (per-wave FIFO): keep the youngest N vmem ops in flight.
#define VM_GATE(N)                                                   \
  do {                                                               \
    asm volatile("s_waitcnt vmcnt(" #N ")" ::: "memory");            \
    __builtin_amdgcn_sched_barrier(0);                               \
  } while (0)

__global__ void cvt_x_kernel(const float* __restrict__ x, unsigned short* __restrict__ xb) {
  const int i = blockIdx.x * blockDim.x + threadIdx.x;
  const float4 f = ((const float4*)x)[i];
  ushort4v u;
  u[0] = f2bf(f.x); u[1] = f2bf(f.y); u[2] = f2bf(f.z); u[3] = f2bf(f.w);
  ((ushort4v*)xb)[i] = u;
}

// 2 WGs per voxel (half = 256 t-rows), XCD-paired for W1 L2-dedup.
// WG = 256 thr = 4 waves; wave w owns 64 t-rows (M=64 -> minimal LDS
// frag-read amplification; acc 128 VGPR; 2 waves/SIMD with 2 WGs/CU =
// two INDEPENDENT 4-wave barrier domains per CU).
// Phase A (16 steps, BK=32): W1 fp32 tile DMA'd via global_load_lds into
// ring-2 G with 1040-B row-pair stride (pad kills the 512-B bank pattern:
// transpose-convert reads become 2-way = free). CVT: thread (w,l) packs
// frag chunks n=w,w+4 -> F dbuf (n*1024 + l*16, conflict-free b128).
// LDS (48.5 KiB/WG): G ring2 [0,33280) + F dbuf [33280,49664) (phase A);
//                    W2L [0,32768) + h1 4x4K [32768,49152)     (phase B).
__global__ __launch_bounds__(256, 2)
void voxel_mlp_kernel(const unsigned short* __restrict__ Xb,
                      const float* __restrict__ W1,
                      const float* __restrict__ b1,
                      const float* __restrict__ W2,
                      const float* __restrict__ b2,
                      const float* __restrict__ W3,
                      const float* __restrict__ b3,
                      float* __restrict__ out) {
  __shared__ __align__(16) char LDS[49664];
  constexpr unsigned GBASE  = 0;
  constexpr unsigned GSLOT  = 16640;   // 16 pairs x 1040 B
  constexpr unsigned FBASE  = 33280;   // 2 x 8192
  constexpr unsigned W2BASE = 0;
  constexpr unsigned H1BASE = 32768;

  const int bid  = blockIdx.x;
  const int xcd  = bid & 7;
  const int gg   = bid >> 3;
  const int half = gg & 1;
  const int v    = (gg >> 1) * 8 + xcd;   // twin halves share an XCD

  const int tid = threadIdx.x;
  const int w   = tid >> 6;    // wave 0..3
  const int l   = tid & 63;
  const int lg  = l >> 4;
  const int ll  = l & 15;

  const float* W1v = W1 + (size_t)v * DD * HH;
  const float* W2v = W2 + (size_t)v * HH * HH;

  // DMA src: wave w, instr p = rows {w*8+2p, +1} (1 KB contiguous), lane 16B
  const size_t gsrc = (size_t)(w * 8) * HH + (size_t)l * 4;

#define G_ISSUE(t)                                                          \
  { const float* gp = W1v + (size_t)(t) * 32 * HH + gsrc;                   \
    const unsigned ld0 = GBASE + (unsigned)((t) & 1) * GSLOT +              \
                         (unsigned)(w * 4) * 1040u;                         \
    _Pragma("unroll") for (int p = 0; p < 4; ++p)                           \
      __builtin_amdgcn_global_load_lds(                                     \
        (const __attribute__((address_space(1))) void*)(gp + p * 2 * HH),   \
        (__attribute__((address_space(3))) void*)(&LDS[ld0 + (unsigned)p * 1040u]), \
        16, 0, 0); }

// transpose-convert tile tau: thread (w,l) builds F[n][l] for n=w, w+4
// G read banks: (260*(k>>1) + n*16 + ll) % 32 -> 2-way (free) by the pad.
#define CVT(tau)                                                            \
  { const unsigned gs = GBASE + (unsigned)((tau) & 1) * GSLOT;              \
    _Pragma("unroll") for (int p = 0; p < 2; ++p) {                         \
      const int n = w + p * 4;                                              \
      ushort8 e;                                                            \
      _Pragma("unroll") for (int j = 0; j < 8; ++j) {                       \
        const int k = lg * 8 + j;                                           \
        const unsigned u = *(const unsigned*)(&LDS[gs +                     \
            (unsigned)((k >> 1) * 1040 + (k & 1) * 512 + (n * 16 + ll) * 4)]); \
        e[j] = (unsigned short)((u + 0x8000u) >> 16);                       \
      }                                                                     \
      *(ushort8*)(&LDS[FBASE + (unsigned)((tau) & 1) * 8192u +              \
                       (unsigned)n * 1024u + (unsigned)l * 16u]) = e;       \
    } }

  // ---- prologue ----
  G_ISSUE(0);
  G_ISSUE(1);
  VM_GATE(4);       // G(0) landed (own); keep G(1)
  lds_barrier();    // G(0) visible across waves
  CVT(0);
  lds_barrier();    // F[0] published

  f32x4 acc1[4][8];
#pragma unroll
  for (int mi = 0; mi < 4; ++mi)
#pragma unroll
    for (int n = 0; n < 8; ++n) acc1[mi][n] = f32x4{0.f, 0.f, 0.f, 0.f};

  // ---- phase A: 16 steps of BK=32 ----
#pragma unroll
  for (int s = 0; s < 16; ++s) {
    // A-frags first (oldest) so the gate retires them with G(s+1)
    bf16x8 aF[4];
#pragma unroll
    for (int mi = 0; mi < 4; ++mi)
      aF[mi] = *(const bf16x8*)(Xb + (size_t)(half * 256 + w * 64 + mi * 16 + ll) * DD +
                                s * 32 + lg * 8);
    __builtin_amdgcn_sched_barrier(0);

    if (s < 14) G_ISSUE(s + 2);
    VM_GATE(4);        // retire A(s) + G(s+1); keep G(s+2) in flight
    lds_barrier();     // G(s+1) visible across waves (cross-wave CVT reads)

    if (s < 15) CVT(s + 1);   // writes F[(s+1)&1]

    // 32 MFMAs on F[s&1]
#pragma unroll
    for (int n = 0; n < 8; ++n) {
      const bf16x8 b = *(const bf16x8*)(&LDS[FBASE + (unsigned)(s & 1) * 8192u +
                                             (unsigned)n * 1024u + (unsigned)l * 16u]);
#pragma unroll
      for (int mi = 0; mi < 4; ++mi)
        acc1[mi][n] = __builtin_amdgcn_mfma_f32_16x16x32_bf16(aF[mi], b, acc1[mi][n], 0, 0, 0);
    }
    lds_barrier();     // publish F[(s+1)&1]; protect F[s&1] for next CVT
  }
#undef G_ISSUE
#undef CVT

  // ---- phase B setup ----
  float b1v[8], b2v[8], w3v[8];
#pragma unroll
  for (int n = 0; n < 8; ++n) {
    b1v[n] = b1[v * HH + n * 16 + ll];
    b2v[n] = b2[v * HH + n * 16 + ll];
    w3v[n] = W3[v * HH + n * 16 + ll];
  }
  const float b3v = b3[v];

  // W2 -> LDS frag-linear: wave w stages ki=w (2 passes of 4 m-blocks)
#pragma unroll
  for (int pass = 0; pass < 2; ++pass) {
    float w2t[4][8];
#pragma unroll
    for (int q = 0; q < 4; ++q)
#pragma unroll
      for (int j = 0; j < 8; ++j)
        w2t[q][j] = W2v[(w * 32 + lg * 8 + j) * HH + (pass * 4 + q) * 16 + ll];
#pragma unroll
    for (int q = 0; q < 4; ++q) {
      ushort8 e;
#pragma unroll
      for (int j = 0; j < 8; ++j) e[j] = f2bf(w2t[q][j]);
      *(ushort8*)(&LDS[W2BASE + (unsigned)w * 8192u + (unsigned)(pass * 4 + q) * 1024u +
                       (unsigned)l * 16u]) = e;
    }
  }
  lds_barrier();   // W2L visible

  const unsigned slot = H1BASE + (unsigned)w * 4096u;  // wave-private 16x128 bf16

  // ---- phase B: layers 2+3, four 16-row blocks per wave ----
#pragma unroll
  for (int mi = 0; mi < 4; ++mi) {
#pragma unroll
    for (int n = 0; n < 8; ++n) {
#pragma unroll
      for (int r = 0; r < 4; ++r) {
        const int tl = lg * 4 + r;
        float hv = acc1[mi][n][r] + b1v[n];
        hv = fmaxf(hv, 0.f);
        const int h = n * 16 + ll;
        const unsigned byte = slot + (unsigned)tl * 256u +
                              (unsigned)((h * 2) ^ ((tl & 7) << 4));
        *(unsigned short*)(&LDS[byte]) = f2bf(hv);
      }
    }
    f32x4 acc2[8];
#pragma unroll
    for (int m = 0; m < 8; ++m) acc2[m] = f32x4{0.f, 0.f, 0.f, 0.f};
#pragma unroll
    for (int ki = 0; ki < 4; ++ki) {
      const int k0 = ki * 32 + lg * 8;
      const unsigned abyte = slot + (unsigned)ll * 256u +
                             (unsigned)((k0 * 2) ^ ((ll & 7) << 4));
      const bf16x8 a2 = *(const bf16x8*)(&LDS[abyte]);
#pragma unroll
      for (int m = 0; m < 8; ++m) {
        const bf16x8 bw = *(const bf16x8*)(&LDS[W2BASE + (unsigned)ki * 8192u +
                                                (unsigned)m * 1024u + (unsigned)l * 16u]);
        acc2[m] = __builtin_amdgcn_mfma_f32_16x16x32_bf16(a2, bw, acc2[m], 0, 0, 0);
      }
    }
#pragma unroll
    for (int r = 0; r < 4; ++r) {
      float p = 0.f;
#pragma unroll
      for (int m = 0; m < 8; ++m)
        p += fmaxf(acc2[m][r] + b2v[m], 0.f) * w3v[m];
      p += __shfl_xor(p, 1);
      p += __shfl_xor(p, 2);
      p += __shfl_xor(p, 4);
      p += __shfl_xor(p, 8);
      if (ll == 0) {
        const int t = half * 256 + w * 64 + mi * 16 + lg * 4 + r;
        out[t * VV + v] = p + b3v;
      }
    }
  }
}

extern "C" void kernel_launch(void* const* d_in, const int* in_sizes, int n_in,
                              void* d_out, int out_size, void* d_ws, size_t ws_size,
                              hipStream_t stream) {
  const float* X  = (const float*)d_in[0];
  const float* W1 = (const float*)d_in[1];
  const float* b1 = (const float*)d_in[2];
  const float* W2 = (const float*)d_in[3];
  const float* b2 = (const float*)d_in[4];
  const float* W3 = (const float*)d_in[5];
  const float* b3 = (const float*)d_in[6];
  float* out = (float*)d_out;

  unsigned short* Xb = (unsigned short*)d_ws;   // 512 KiB bf16 X

  cvt_x_kernel<<<256, 256, 0, stream>>>(X, Xb);
  voxel_mlp_kernel<<<VV * 2, 256, 0, stream>>>(Xb, W1, b1, W2, b2, W3, b3, out);
}

// Round 13
// 282.685 us; speedup vs baseline: 1.2152x; 1.0369x over previous
//
#include <hip/hip_runtime.h>
#include <hip/hip_bf16.h>

#define TT 512
#define DD 512
#define VV 2048
#define HH 128

typedef __attribute__((ext_vector_type(8))) short bf16x8;
typedef __attribute__((ext_vector_type(8))) unsigned short ushort8;
typedef __attribute__((ext_vector_type(4))) unsigned short ushort4v;
typedef __attribute__((ext_vector_type(4))) float f32x4;

__device__ __forceinline__ unsigned short f2bf(float f) {
  union { __hip_bfloat16 b; unsigned short u; } cv;
  cv.b = __float2bfloat16(f);
  return cv.u;
}

// LDS-only barrier: orders ds ops across waves without draining vmcnt.
__device__ __forceinline__ void lds_barrier() {
  asm volatile("s_waitcnt lgkmcnt(0)\n\ts_barrier" ::: "memory");
}

// Counted vmem gate (per-wave FIFO): keep the youngest N vmem ops in flight.
#define VM_GATE(N)                                                   \
  do {                                                               \
    asm volatile("s_waitcnt vmcnt(" #N ")" ::: "memory");            \
    __builtin_amdgcn_sched_barrier(0);                               \
  } while (0)

__global__ void cvt_x_kernel(const float* __restrict__ x, unsigned short* __restrict__ xb) {
  const int i = blockIdx.x * blockDim.x + threadIdx.x;
  const float4 f = ((const float4*)x)[i];
  ushort4v u;
  u[0] = f2bf(f.x); u[1] = f2bf(f.y); u[2] = f2bf(f.z); u[3] = f2bf(f.w);
  ((ushort4v*)xb)[i] = u;
}

// 2 WGs per voxel (half = 256 t-rows), XCD-paired for W1 L2-dedup.
// WG = 256 thr = 4 waves; wave w owns 64 t-rows. Phase A (16 steps, BK=32):
// W1 fp32 tile DMA'd (global_load_lds) into ring-3 G (1040-B row-pair
// stride: transpose-CVT reads are 2-way = free). A-frags double-buffered
// (issued with the G stream; VM_GATE(8) retires {G(s+1),A(s)} and keeps
// {G(s+2),A(s+1)} in flight). ONE lds_barrier per step: ring-3 makes the
// DMA-written slot disjoint from both slots readable under 1-barrier skew.
// LDS (64.75 KiB/WG): G ring3 [0,49920) + F dbuf [49920,66304) (phase A);
//                     W2L [0,32768) + h1 4x4K [32768,49152)    (phase B).
__global__ __launch_bounds__(256, 2)
void voxel_mlp_kernel(const unsigned short* __restrict__ Xb,
                      const float* __restrict__ W1,
                      const float* __restrict__ b1,
                      const float* __restrict__ W2,
                      const float* __restrict__ b2,
                      const float* __restrict__ W3,
                      const float* __restrict__ b3,
                      float* __restrict__ out) {
  __shared__ __align__(16) char LDS[66304];
  constexpr unsigned GBASE  = 0;
  constexpr unsigned GSLOT  = 16640;   // 16 pairs x 1040 B
  constexpr unsigned FBASE  = 49920;   // 2 x 8192
  constexpr unsigned W2BASE = 0;
  constexpr unsigned H1BASE = 32768;

  const int bid  = blockIdx.x;
  const int xcd  = bid & 7;
  const int gg   = bid >> 3;
  const int half = gg & 1;
  const int v    = (gg >> 1) * 8 + xcd;   // twin halves share an XCD

  const int tid = threadIdx.x;
  const int w   = tid >> 6;    // wave 0..3
  const int l   = tid & 63;
  const int lg  = l >> 4;
  const int ll  = l & 15;

  const float* W1v = W1 + (size_t)v * DD * HH;
  const float* W2v = W2 + (size_t)v * HH * HH;

  // DMA src: wave w, instr p = rows {w*8+2p, +1} (1 KB contiguous), lane 16B
  const size_t gsrc = (size_t)(w * 8) * HH + (size_t)l * 4;

#define G_ISSUE(t)                                                          \
  { const float* gp = W1v + (size_t)(t) * 32 * HH + gsrc;                   \
    const unsigned ld0 = GBASE + (unsigned)((t) % 3) * GSLOT +              \
                         (unsigned)(w * 4) * 1040u;                         \
    _Pragma("unroll") for (int p = 0; p < 4; ++p)                           \
      __builtin_amdgcn_global_load_lds(                                     \
        (const __attribute__((address_space(1))) void*)(gp + p * 2 * HH),   \
        (__attribute__((address_space(3))) void*)(&LDS[ld0 + (unsigned)p * 1040u]), \
        16, 0, 0); }

// transpose-convert tile tau: thread (w,l) builds F[n][l] for n=w, w+4
// G read banks: (16*lg + ll + const) % 32 -> 2-way (free) via the 1040 pad.
#define CVT(tau)                                                            \
  { const unsigned gs = GBASE + (unsigned)((tau) % 3) * GSLOT;              \
    _Pragma("unroll") for (int p = 0; p < 2; ++p) {                         \
      const int n = w + p * 4;                                              \
      ushort8 e;                                                            \
      _Pragma("unroll") for (int j = 0; j < 8; ++j) {                       \
        const int k = lg * 8 + j;                                           \
        const unsigned u = *(const unsigned*)(&LDS[gs +                     \
            (unsigned)((k >> 1) * 1040 + (k & 1) * 512 + (n * 16 + ll) * 4)]); \
        e[j] = (unsigned short)((u + 0x8000u) >> 16);                       \
      }                                                                     \
      *(ushort8*)(&LDS[FBASE + (unsigned)((tau) & 1) * 8192u +              \
                       (unsigned)n * 1024u + (unsigned)l * 16u]) = e;       \
    } }

// A-frags for step st into dbuf slot st&1 (4 x global_load_dwordx4)
#define ISSUE_A(st)                                                         \
  { _Pragma("unroll") for (int mi = 0; mi < 4; ++mi)                        \
      aS[(st) & 1][mi] = *(const bf16x8*)(Xb +                              \
          (size_t)(half * 256 + w * 64 + mi * 16 + ll) * DD +               \
          (st) * 32 + lg * 8); }

  bf16x8 aS[2][4];

  // ---- prologue ----
  G_ISSUE(0);
  G_ISSUE(1);
  ISSUE_A(0);
  VM_GATE(8);       // retire G(0); keep G(1)+A(0) in flight
  lds_barrier();    // G(0) visible across waves
  CVT(0);           // -> F[0] (published by the loop's first barrier)

  f32x4 acc1[4][8];
#pragma unroll
  for (int mi = 0; mi < 4; ++mi)
#pragma unroll
    for (int n = 0; n < 8; ++n) acc1[mi][n] = f32x4{0.f, 0.f, 0.f, 0.f};

  // ---- phase A: 16 steps of BK=32, ONE barrier per step ----
#pragma unroll
  for (int s = 0; s < 16; ++s) {
    if (s < 14) G_ISSUE(s + 2);
    if (s < 15) ISSUE_A(s + 1);
    if (s < 14)      { VM_GATE(8); }   // retire G(s+1)+A(s); keep G(s+2)+A(s+1)
    else if (s == 14){ VM_GATE(4); }   // retire G(15)+A(14); keep A(15)
    else             { VM_GATE(0); }   // retire A(15)
    lds_barrier();   // G(s+1) + F[s&1] visible to all waves

    if (s < 15) CVT(s + 1);   // reads G ring slot (s+1)%3; writes F[(s+1)&1]

    // 32 MFMAs on F[s&1] x aS[s&1]
#pragma unroll
    for (int n = 0; n < 8; ++n) {
      const bf16x8 b = *(const bf16x8*)(&LDS[FBASE + (unsigned)(s & 1) * 8192u +
                                             (unsigned)n * 1024u + (unsigned)l * 16u]);
#pragma unroll
      for (int mi = 0; mi < 4; ++mi)
        acc1[mi][n] = __builtin_amdgcn_mfma_f32_16x16x32_bf16(aS[s & 1][mi], b, acc1[mi][n], 0, 0, 0);
    }
  }
#undef G_ISSUE
#undef CVT
#undef ISSUE_A

  // ---- phase B setup (G/F DMA all retired; G region dead) ----
  float b1v[8], b2v[8], w3v[8];
#pragma unroll
  for (int n = 0; n < 8; ++n) {
    b1v[n] = b1[v * HH + n * 16 + ll];
    b2v[n] = b2[v * HH + n * 16 + ll];
    w3v[n] = W3[v * HH + n * 16 + ll];
  }
  const float b3v = b3[v];

  // W2 -> LDS frag-linear: wave w stages ki=w (2 passes of 4 m-blocks)
#pragma unroll
  for (int pass = 0; pass < 2; ++pass) {
    float w2t[4][8];
#pragma unroll
    for (int q = 0; q < 4; ++q)
#pragma unroll
      for (int j = 0; j < 8; ++j)
        w2t[q][j] = W2v[(w * 32 + lg * 8 + j) * HH + (pass * 4 + q) * 16 + ll];
#pragma unroll
    for (int q = 0; q < 4; ++q) {
      ushort8 e;
#pragma unroll
      for (int j = 0; j < 8; ++j) e[j] = f2bf(w2t[q][j]);
      *(ushort8*)(&LDS[W2BASE + (unsigned)w * 8192u + (unsigned)(pass * 4 + q) * 1024u +
                       (unsigned)l * 16u]) = e;
    }
  }
  lds_barrier();   // W2L visible

  const unsigned slot = H1BASE + (unsigned)w * 4096u;  // wave-private 16x128 bf16

  // ---- phase B: layers 2+3, four 16-row blocks per wave ----
#pragma unroll
  for (int mi = 0; mi < 4; ++mi) {
#pragma unroll
    for (int n = 0; n < 8; ++n) {
#pragma unroll
      for (int r = 0; r < 4; ++r) {
        const int tl = lg * 4 + r;
        float hv = acc1[mi][n][r] + b1v[n];
        hv = fmaxf(hv, 0.f);
        const int h = n * 16 + ll;
        const unsigned byte = slot + (unsigned)tl * 256u +
                              (unsigned)((h * 2) ^ ((tl & 7) << 4));
        *(unsigned short*)(&LDS[byte]) = f2bf(hv);
      }
    }
    f32x4 acc2[8];
#pragma unroll
    for (int m = 0; m < 8; ++m) acc2[m] = f32x4{0.f, 0.f, 0.f, 0.f};
#pragma unroll
    for (int ki = 0; ki < 4; ++ki) {
      const int k0 = ki * 32 + lg * 8;
      const unsigned abyte = slot + (unsigned)ll * 256u +
                             (unsigned)((k0 * 2) ^ ((ll & 7) << 4));
      const bf16x8 a2 = *(const bf16x8*)(&LDS[abyte]);
#pragma unroll
      for (int m = 0; m < 8; ++m) {
        const bf16x8 bw = *(const bf16x8*)(&LDS[W2BASE + (unsigned)ki * 8192u +
                                                (unsigned)m * 1024u + (unsigned)l * 16u]);
        acc2[m] = __builtin_amdgcn_mfma_f32_16x16x32_bf16(a2, bw, acc2[m], 0, 0, 0);
      }
    }
#pragma unroll
    for (int r = 0; r < 4; ++r) {
      float p = 0.f;
#pragma unroll
      for (int m = 0; m < 8; ++m)
        p += fmaxf(acc2[m][r] + b2v[m], 0.f) * w3v[m];
      p += __shfl_xor(p, 1);
      p += __shfl_xor(p, 2);
      p += __shfl_xor(p, 4);
      p += __shfl_xor(p, 8);
      if (ll == 0) {
        const int t = half * 256 + w * 64 + mi * 16 + lg * 4 + r;
        out[t * VV + v] = p + b3v;
      }
    }
  }
}

extern "C" void kernel_launch(void* const* d_in, const int* in_sizes, int n_in,
                              void* d_out, int out_size, void* d_ws, size_t ws_size,
                              hipStream_t stream) {
  const float* X  = (const float*)d_in[0];
  const float* W1 = (const float*)d_in[1];
  const float* b1 = (const float*)d_in[2];
  const float* W2 = (const float*)d_in[3];
  const float* b2 = (const float*)d_in[4];
  const float* W3 = (const float*)d_in[5];
  const float* b3 = (const float*)d_in[6];
  float* out = (float*)d_out;

  unsigned short* Xb = (unsigned short*)d_ws;   // 512 KiB bf16 X

  cvt_x_kernel<<<256, 256, 0, stream>>>(X, Xb);
  voxel_mlp_kernel<<<VV * 2, 256, 0, stream>>>(Xb, W1, b1, W2, b2, W3, b3, out);
}